// Round 5
// baseline (66.809 us; speedup 1.0000x reference)
//
#include <hip/hip_runtime.h>

#define L_IN   2048
#define C_IN   512
#define L_OUT  2045
#define XT_PAD 21
#define GA     514   // out2 g-row stride in elems (32 a * 16 m + 2 pad) -> conflict-free

typedef short short8 __attribute__((ext_vector_type(8)));
typedef short short4v __attribute__((ext_vector_type(4)));
typedef float float4v __attribute__((ext_vector_type(4)));

__device__ __forceinline__ unsigned short bf16r(float f) {
    unsigned u = __float_as_uint(f);
    unsigned r = (u + 0x7FFFu + ((u >> 16) & 1u)) >> 16;
    return (unsigned short)r;
}

// ---------------- kernel 1: build W21/W43 in MFMA fragment layout (verified R3) ----------
__global__ __launch_bounds__(256)
void build_wf(const float* __restrict__ tw, unsigned short* __restrict__ W21f,
              unsigned short* __restrict__ W43f) {
    int id = blockIdx.x * 256 + threadIdx.x;
    if (id < 65536) {
        int p = id & 7, lane = (id >> 3) & 63, oh = (id >> 9) & 1, g = id >> 10;
        int a = oh * 16 + (lane & 15);
        int e = ((lane >> 4) & 3) * 8 + p;
        int r2 = a >> 2, d2 = a & 3, c2 = e >> 2, c1 = e & 3;
        float v = tw[8192 + ((g * 4 + d2) * 8 + r2) * 8 + c2]
                * tw[(g * 8 + c2) * 16 + d2 * 4 + c1];
        W21f[id] = bf16r(v);
    } else if (id < 98304) {
        int id2 = id - 65536;
        int p = id2 & 7, lane = (id2 >> 3) & 63, kh = (id2 >> 9) & 1, s = id2 >> 10;
        int u = lane & 15;
        int w = kh * 32 + ((lane >> 4) & 3) * 8 + p;
        int r4 = u >> 1, hi = u & 1, d4 = hi * 32 + s, p2 = w >> 3, c3 = w & 7;
        float v = 0.f;
        #pragma unroll
        for (int lo = 0; lo < 2; ++lo)
            v += tw[32768 + (d4 * 8 + r4) * 16 + (2 * p2 + lo)]
               * tw[24576 + ((p2 * 32 + s) * 4 + (2 * lo + hi)) * 8 + c3];
        W43f[id2] = bf16r(v);
    }
}

// ---------------- kernel 2: transpose x (b,c,l) f32 -> xT (b,l,c) bf16 (verified R3) -----
__global__ __launch_bounds__(256)
void transpose_x(const float* __restrict__ x, unsigned short* __restrict__ xT) {
    __shared__ unsigned short tile[64 * 66];
    const int lt = blockIdx.x, ct = blockIdx.y, b = blockIdx.z;
    const int l0 = lt * 64, c0 = ct * 64;
    const int t = threadIdx.x;
    const float* xb = x + ((size_t)b * C_IN + c0) * L_IN + l0;

    #pragma unroll
    for (int pass = 0; pass < 4; ++pass) {
        int c  = pass * 16 + (t >> 4);
        int lc = (t & 15) * 4;
        float4 v = *reinterpret_cast<const float4*>(xb + (size_t)c * L_IN + lc);
        unsigned u0 = (unsigned)bf16r(v.x) | ((unsigned)bf16r(v.y) << 16);
        unsigned u1 = (unsigned)bf16r(v.z) | ((unsigned)bf16r(v.w) << 16);
        *(unsigned*)&tile[c * 66 + lc]     = u0;
        *(unsigned*)&tile[c * 66 + lc + 2] = u1;
    }
    __syncthreads();

    const int l = t >> 2, cc = (t & 3) * 16;
    unsigned short v[16];
    #pragma unroll
    for (int j = 0; j < 16; ++j) v[j] = tile[(cc + j) * 66 + l];
    unsigned short* dst = xT + ((size_t)b * L_IN + l0 + l) * C_IN + c0 + cc;
    *(uint4*)dst       = *(const uint4*)&v[0];
    *(uint4*)(dst + 8) = *(const uint4*)&v[8];
}

// ---------------- kernel 3: two-stage block MFMA, l-tile=16, scalar stage-B reads --------
// Stage A (swapped operands): D = mfma(vfrag(m), w21frag(a)) -> lane: a=oh*16+lr, m=lh*4+i
//   packed b64 write to out2[g][a][m16]  (elem = g*GA + a*16 + m)
// Stage B: lane gathers B[k=g][col=m=lr] via 16 scalar u16 reads (2-way banks, free)
__global__ __launch_bounds__(512)
void debut_mfma(const unsigned short* __restrict__ W21f,
                const unsigned short* __restrict__ W43f,
                const unsigned short* __restrict__ xT,
                const float* __restrict__ bias, float* __restrict__ out) {
    extern __shared__ __align__(16) unsigned short out2[];   // 64 * GA elems = 65792 B

    const int blk = blockIdx.x;          // 2048 = 16 b * 128 ltiles
    const int lt = blk & 127, b = blk >> 7;
    const int l0 = lt * 16;
    const int t = threadIdx.x;
    const int lane = t & 63, wv = t >> 6;        // 8 waves
    const int lr = lane & 15, lh = lane >> 4;

    const unsigned short* xTb = xT + (size_t)b * L_IN * C_IN;

    // per-wave uniform koff (g = wv*8..wv*8+7 -> g>>4 = wv>>1)
    const int koff = wv >> 1;
    int lx = l0 + lr + koff; if (lx > L_IN - 1) lx = L_IN - 1;
    const unsigned short* xrow = xTb + (size_t)lx * C_IN + lh * 8;

    // hoist stage-B A-operand loads (global, independent of LDS)
    short8 wa[4][2];
    #pragma unroll
    for (int si = 0; si < 4; ++si) {
        int s = wv * 4 + si;
        wa[si][0] = *(const short8*)(W43f + ((size_t)(s * 2 + 0) * 64 + lane) * 8);
        wa[si][1] = *(const short8*)(W43f + ((size_t)(s * 2 + 1) * 64 + lane) * 8);
    }

    // ---- stage A: wave wv handles g = wv*8 .. wv*8+7 ----
    #pragma unroll
    for (int gi = 0; gi < 8; ++gi) {
        const int g = wv * 8 + gi;
        const int c0 = (g & 15) * 32;
        short8 vfrag = *(const short8*)(xrow + c0);
        #pragma unroll
        for (int oh = 0; oh < 2; ++oh) {
            short8 wfrag = *(const short8*)(W21f + ((size_t)(g * 2 + oh) * 64 + lane) * 8);
            float4v acc = {};
            acc = __builtin_amdgcn_mfma_f32_16x16x32_bf16(vfrag, wfrag, acc, 0, 0, 0);
            // lane holds: a = oh*16+lr (D col), m = lh*4+i (D row) -> one b64 write
            unsigned short pk[4];
            #pragma unroll
            for (int i = 0; i < 4; ++i) pk[i] = bf16r(acc[i]);
            const int a = oh * 16 + lr;
            *(short4v*)&out2[g * GA + a * 16 + lh * 4] = *(const short4v*)pk;
        }
    }
    __syncthreads();

    // ---- stage B: wave wv handles s = wv*4 .. wv*4+3 ----
    const int lpos = l0 + lr;
    #pragma unroll
    for (int si = 0; si < 4; ++si) {
        const int s = wv * 4 + si;
        // lane needs out2[g = kh*32 + lh*8 + j][a=s][m=lr]
        short8 b0, b1;
        #pragma unroll
        for (int j = 0; j < 8; ++j)
            b0[j] = (short)out2[(size_t)(lh * 8 + j) * GA + s * 16 + lr];
        #pragma unroll
        for (int j = 0; j < 8; ++j)
            b1[j] = (short)out2[(size_t)(32 + lh * 8 + j) * GA + s * 16 + lr];
        float4v acc = {};
        acc = __builtin_amdgcn_mfma_f32_16x16x32_bf16(wa[si][0], b0, acc, 0, 0, 0);
        acc = __builtin_amdgcn_mfma_f32_16x16x32_bf16(wa[si][1], b1, acc, 0, 0, 0);
        if (lpos < L_OUT) {
            #pragma unroll
            for (int i = 0; i < 4; ++i) {
                int o4 = s + 32 * (lh * 4 + i);
                out[((size_t)(b * 512 + o4)) * L_OUT + lpos] = acc[i] + bias[o4];
            }
        }
    }
}

// ---------------- fallback (round-1 kernel, used if ws too small) ----------------
__global__ __launch_bounds__(256)
void debut_fused_kernel(const float* __restrict__ x,
                        const float* __restrict__ tw,
                        const float* __restrict__ bias,
                        float* __restrict__ out)
{
    __shared__ float xt[C_IN * XT_PAD];
    __shared__ float bufA[2048];
    __shared__ float bufB[2048];
    const int tile = blockIdx.x, b = blockIdx.y;
    const int l0 = tile * 16;
    const int tid = threadIdx.x;
    const float* xb = x + (size_t)b * C_IN * L_IN;
    for (int idx = tid; idx < C_IN * 19; idx += 256) {
        int c = idx / 19, ll = idx - c * 19, l = l0 + ll;
        xt[c * XT_PAD + ll] = (l < L_IN) ? xb[c * L_IN + l] : 0.0f;
    }
    __syncthreads();
    const float* t1 = tw; const float* t2 = tw + 8192;
    const float* t3 = tw + 24576; const float* t4 = tw + 32768;
    for (int rr = 0; rr < 16; ++rr) {
        const int l = l0 + rr;
        if (l >= L_OUT) break;
        #pragma unroll
        for (int i = 0; i < 8; ++i) {
            int o = tid + 256 * i, gb = o >> 2, k = gb >> 7, cb = (gb & 127) << 2;
            const float4 tq = *reinterpret_cast<const float4*>(t1 + o * 4);
            const float* xp = &xt[cb * XT_PAD + rr + k];
            bufA[o] = tq.x * xp[0] + tq.y * xp[XT_PAD] + tq.z * xp[2 * XT_PAD] + tq.w * xp[3 * XT_PAD];
        }
        __syncthreads();
        #pragma unroll
        for (int i = 0; i < 8; ++i) {
            int o = tid + 256 * i, gb = o >> 5, r = (o >> 2) & 7, d = o & 3;
            const float* tp = t2 + (((gb << 2) + d) * 8 + r) * 8;
            const float* ip = &bufA[(gb << 5) + d];
            float acc = 0.0f;
            #pragma unroll
            for (int c = 0; c < 8; ++c) acc += tp[c] * ip[c << 2];
            bufB[o] = acc;
        }
        __syncthreads();
        #pragma unroll
        for (int i = 0; i < 4; ++i) {
            int o = tid + 256 * i, gb = o >> 7, r = (o >> 5) & 3, d = o & 31;
            const float* tp = t3 + (((gb << 5) + d) * 4 + r) * 8;
            const float* ip = &bufB[(gb << 8) + d];
            float acc = 0.0f;
            #pragma unroll
            for (int c = 0; c < 8; ++c) acc += tp[c] * ip[c << 5];
            bufA[o] = acc;
        }
        __syncthreads();
        #pragma unroll
        for (int i = 0; i < 2; ++i) {
            int o = tid + 256 * i, r = o >> 6, d = o & 63;
            const float* tp = t4 + ((d << 3) + r) * 16;
            float acc = 0.0f;
            #pragma unroll
            for (int c = 0; c < 16; ++c) acc += tp[c] * bufA[(c << 6) + d];
            out[((size_t)(b * 512 + o)) * L_OUT + l] = acc + bias[o];
        }
        __syncthreads();
    }
}

extern "C" void kernel_launch(void* const* d_in, const int* in_sizes, int n_in,
                              void* d_out, int out_size, void* d_ws, size_t ws_size,
                              hipStream_t stream) {
    const float* x    = (const float*)d_in[0];
    const float* tw   = (const float*)d_in[1];
    const float* bias = (const float*)d_in[2];
    float* out = (float*)d_out;

    const size_t W21_B = 65536 * 2;                       // 128 KB
    const size_t W43_B = 32768 * 2;                       // 64 KB
    const size_t XT_B  = (size_t)16 * L_IN * C_IN * 2;    // 32 MB
    const int    LDS_B = 64 * GA * 2;                     // 65792

    if (ws_size < W21_B + W43_B + XT_B) {
        dim3 grid(128, 16);
        debut_fused_kernel<<<grid, dim3(256), 0, stream>>>(x, tw, bias, out);
        return;
    }

    unsigned short* W21f = (unsigned short*)d_ws;
    unsigned short* W43f = (unsigned short*)((char*)d_ws + W21_B);
    unsigned short* xTd  = (unsigned short*)((char*)d_ws + W21_B + W43_B);

    (void)hipFuncSetAttribute((const void*)debut_mfma,
                              hipFuncAttributeMaxDynamicSharedMemorySize, LDS_B);

    build_wf<<<dim3(384), dim3(256), 0, stream>>>(tw, W21f, W43f);
    transpose_x<<<dim3(32, 8, 16), dim3(256), 0, stream>>>(x, xTd);
    debut_mfma<<<dim3(2048), dim3(512), (size_t)LDS_B, stream>>>(W21f, W43f, xTd, bias, out);
}

// Round 6
// 65.333 us; speedup vs baseline: 1.0226x; 1.0226x over previous
//
#include <hip/hip_runtime.h>

#define L_IN   2048
#define C_IN   512
#define L_OUT  2045
#define XT_PAD 21
#define GPROW  580   // out2 gp-row stride (elems): 8 mh * 72 + 4 pad -> 2-way banks both sides
#define MHS    72    // mh stride in elems (36 dwords, ≡4 mod 32 banks)

typedef short short8 __attribute__((ext_vector_type(8)));
typedef float float4v __attribute__((ext_vector_type(4)));

__device__ __forceinline__ unsigned short bf16r(float f) {
    unsigned u = __float_as_uint(f);
    unsigned r = (u + 0x7FFFu + ((u >> 16) & 1u)) >> 16;
    return (unsigned short)r;
}

// ---------------- kernel 1: build W21/W43 in MFMA fragment layout (verified R3/R5) -------
__global__ __launch_bounds__(256)
void build_wf(const float* __restrict__ tw, unsigned short* __restrict__ W21f,
              unsigned short* __restrict__ W43f) {
    int id = blockIdx.x * 256 + threadIdx.x;
    if (id < 65536) {
        int p = id & 7, lane = (id >> 3) & 63, oh = (id >> 9) & 1, g = id >> 10;
        int a = oh * 16 + (lane & 15);
        int e = ((lane >> 4) & 3) * 8 + p;
        int r2 = a >> 2, d2 = a & 3, c2 = e >> 2, c1 = e & 3;
        float v = tw[8192 + ((g * 4 + d2) * 8 + r2) * 8 + c2]
                * tw[(g * 8 + c2) * 16 + d2 * 4 + c1];
        W21f[id] = bf16r(v);
    } else if (id < 98304) {
        int id2 = id - 65536;
        int p = id2 & 7, lane = (id2 >> 3) & 63, kh = (id2 >> 9) & 1, s = id2 >> 10;
        int u = lane & 15;
        int w = kh * 32 + ((lane >> 4) & 3) * 8 + p;
        int r4 = u >> 1, hi = u & 1, d4 = hi * 32 + s, p2 = w >> 3, c3 = w & 7;
        float v = 0.f;
        #pragma unroll
        for (int lo = 0; lo < 2; ++lo)
            v += tw[32768 + (d4 * 8 + r4) * 16 + (2 * p2 + lo)]
               * tw[24576 + ((p2 * 32 + s) * 4 + (2 * lo + hi)) * 8 + c3];
        W43f[id2] = bf16r(v);
    }
}

// ---------------- kernel 2: transpose x (b,c,l) f32 -> xT (b,l,c) bf16 (verified R3) -----
__global__ __launch_bounds__(256)
void transpose_x(const float* __restrict__ x, unsigned short* __restrict__ xT) {
    __shared__ unsigned short tile[64 * 66];
    const int lt = blockIdx.x, ct = blockIdx.y, b = blockIdx.z;
    const int l0 = lt * 64, c0 = ct * 64;
    const int t = threadIdx.x;
    const float* xb = x + ((size_t)b * C_IN + c0) * L_IN + l0;

    #pragma unroll
    for (int pass = 0; pass < 4; ++pass) {
        int c  = pass * 16 + (t >> 4);
        int lc = (t & 15) * 4;
        float4 v = *reinterpret_cast<const float4*>(xb + (size_t)c * L_IN + lc);
        unsigned u0 = (unsigned)bf16r(v.x) | ((unsigned)bf16r(v.y) << 16);
        unsigned u1 = (unsigned)bf16r(v.z) | ((unsigned)bf16r(v.w) << 16);
        *(unsigned*)&tile[c * 66 + lc]     = u0;
        *(unsigned*)&tile[c * 66 + lc + 2] = u1;
    }
    __syncthreads();

    const int l = t >> 2, cc = (t & 3) * 16;
    unsigned short v[16];
    #pragma unroll
    for (int j = 0; j < 16; ++j) v[j] = tile[(cc + j) * 66 + l];
    unsigned short* dst = xT + ((size_t)b * L_IN + l0 + l) * C_IN + c0 + cc;
    *(uint4*)dst       = *(const uint4*)&v[0];
    *(uint4*)(dst + 8) = *(const uint4*)&v[8];
}

// ---------------- kernel 3: phased two-stage block MFMA -------------------------------
// Phase p (p=0: g 0..31, p=1: g 32..63):
//   Stage A (swapped operands): wave wv computes g = p*32 + wv*4 + gi, writes D (a,m)
//     as 2x ds_write_b32 at elem = gp*GPROW + (m>>1)*MHS + a*2 + (m&1), gp = g - p*32.
//   Stage B: wave wv accumulates s = wv*4+si with wa[si][p] against out2 rows gp=lh*8+j.
// accB persists in registers across phases; store once at the end.
__global__ __launch_bounds__(512)
void debut_mfma(const unsigned short* __restrict__ W21f,
                const unsigned short* __restrict__ W43f,
                const unsigned short* __restrict__ xT,
                const float* __restrict__ bias, float* __restrict__ out) {
    __shared__ __align__(16) unsigned short out2[32 * GPROW];   // 37120 B

    // XCD-aware bijective swizzle (2048 blocks, 8 XCDs, 256 each)
    const int bid = blockIdx.x;
    const int swz = (bid & 7) * 256 + (bid >> 3);
    const int lt = swz & 127, b = swz >> 7;
    const int l0 = lt * 16;
    const int t = threadIdx.x;
    const int lane = t & 63, wv = t >> 6;        // 8 waves
    const int lr = lane & 15, lh = lane >> 4;

    const unsigned short* xTb = xT + (size_t)b * L_IN * C_IN;

    // hoist stage-B A-operand loads (L2-resident, independent of LDS)
    short8 wa[4][2];
    #pragma unroll
    for (int si = 0; si < 4; ++si) {
        int s = wv * 4 + si;
        wa[si][0] = *(const short8*)(W43f + ((size_t)(s * 2 + 0) * 64 + lane) * 8);
        wa[si][1] = *(const short8*)(W43f + ((size_t)(s * 2 + 1) * 64 + lane) * 8);
    }

    float4v accB[4] = {};

    #pragma unroll
    for (int p = 0; p < 2; ++p) {
        // ---- stage A: wave wv handles g = p*32 + wv*4 .. +3 ----
        const int koff = 2 * p + (wv >> 2);
        int lx = l0 + lr + koff; if (lx > L_IN - 1) lx = L_IN - 1;
        const unsigned short* xrow = xTb + (size_t)lx * C_IN + lh * 8;

        #pragma unroll
        for (int gi = 0; gi < 4; ++gi) {
            const int gp = wv * 4 + gi;          // slot row (= g - p*32)
            const int g  = p * 32 + gp;
            const int c0 = ((wv * 4 + gi) & 15) * 32;
            short8 vfrag = *(const short8*)(xrow + c0);
            #pragma unroll
            for (int oh = 0; oh < 2; ++oh) {
                short8 wfrag = *(const short8*)(W21f + ((size_t)(g * 2 + oh) * 64 + lane) * 8);
                float4v acc = {};
                acc = __builtin_amdgcn_mfma_f32_16x16x32_bf16(vfrag, wfrag, acc, 0, 0, 0);
                // lane holds: a = oh*16+lr (col), m = lh*4+i (row)
                unsigned short pk[4];
                #pragma unroll
                for (int i = 0; i < 4; ++i) pk[i] = bf16r(acc[i]);
                const int a = oh * 16 + lr;
                unsigned lo = (unsigned)pk[0] | ((unsigned)pk[1] << 16);
                unsigned hi = (unsigned)pk[2] | ((unsigned)pk[3] << 16);
                *(unsigned*)&out2[gp * GPROW + (2 * lh + 0) * MHS + a * 2] = lo;
                *(unsigned*)&out2[gp * GPROW + (2 * lh + 1) * MHS + a * 2] = hi;
            }
        }
        __syncthreads();

        // ---- stage B: wave wv accumulates s = wv*4 .. +3 over this phase's 32 g ----
        #pragma unroll
        for (int si = 0; si < 4; ++si) {
            const int s = wv * 4 + si;
            short8 bb;
            #pragma unroll
            for (int j = 0; j < 8; ++j)
                bb[j] = (short)out2[(size_t)(lh * 8 + j) * GPROW + (lr >> 1) * MHS + s * 2 + (lr & 1)];
            accB[si] = __builtin_amdgcn_mfma_f32_16x16x32_bf16(wa[si][p], bb, accB[si], 0, 0, 0);
        }
        if (p == 0) __syncthreads();   // protect out2 before phase-1 overwrite
    }

    // ---- store ----
    const int lpos = l0 + lr;
    if (lpos < L_OUT) {
        #pragma unroll
        for (int si = 0; si < 4; ++si) {
            const int s = wv * 4 + si;
            #pragma unroll
            for (int i = 0; i < 4; ++i) {
                int o4 = s + 32 * (lh * 4 + i);
                out[((size_t)(b * 512 + o4)) * L_OUT + lpos] = accB[si][i] + bias[o4];
            }
        }
    }
}

// ---------------- fallback (round-1 kernel, used if ws too small) ----------------
__global__ __launch_bounds__(256)
void debut_fused_kernel(const float* __restrict__ x,
                        const float* __restrict__ tw,
                        const float* __restrict__ bias,
                        float* __restrict__ out)
{
    __shared__ float xt[C_IN * XT_PAD];
    __shared__ float bufA[2048];
    __shared__ float bufB[2048];
    const int tile = blockIdx.x, b = blockIdx.y;
    const int l0 = tile * 16;
    const int tid = threadIdx.x;
    const float* xb = x + (size_t)b * C_IN * L_IN;
    for (int idx = tid; idx < C_IN * 19; idx += 256) {
        int c = idx / 19, ll = idx - c * 19, l = l0 + ll;
        xt[c * XT_PAD + ll] = (l < L_IN) ? xb[c * L_IN + l] : 0.0f;
    }
    __syncthreads();
    const float* t1 = tw; const float* t2 = tw + 8192;
    const float* t3 = tw + 24576; const float* t4 = tw + 32768;
    for (int rr = 0; rr < 16; ++rr) {
        const int l = l0 + rr;
        if (l >= L_OUT) break;
        #pragma unroll
        for (int i = 0; i < 8; ++i) {
            int o = tid + 256 * i, gb = o >> 2, k = gb >> 7, cb = (gb & 127) << 2;
            const float4 tq = *reinterpret_cast<const float4*>(t1 + o * 4);
            const float* xp = &xt[cb * XT_PAD + rr + k];
            bufA[o] = tq.x * xp[0] + tq.y * xp[XT_PAD] + tq.z * xp[2 * XT_PAD] + tq.w * xp[3 * XT_PAD];
        }
        __syncthreads();
        #pragma unroll
        for (int i = 0; i < 8; ++i) {
            int o = tid + 256 * i, gb = o >> 5, r = (o >> 2) & 7, d = o & 3;
            const float* tp = t2 + (((gb << 2) + d) * 8 + r) * 8;
            const float* ip = &bufA[(gb << 5) + d];
            float acc = 0.0f;
            #pragma unroll
            for (int c = 0; c < 8; ++c) acc += tp[c] * ip[c << 2];
            bufB[o] = acc;
        }
        __syncthreads();
        #pragma unroll
        for (int i = 0; i < 4; ++i) {
            int o = tid + 256 * i, gb = o >> 7, r = (o >> 5) & 3, d = o & 31;
            const float* tp = t3 + (((gb << 5) + d) * 4 + r) * 8;
            const float* ip = &bufB[(gb << 8) + d];
            float acc = 0.0f;
            #pragma unroll
            for (int c = 0; c < 8; ++c) acc += tp[c] * ip[c << 5];
            bufA[o] = acc;
        }
        __syncthreads();
        #pragma unroll
        for (int i = 0; i < 2; ++i) {
            int o = tid + 256 * i, r = o >> 6, d = o & 63;
            const float* tp = t4 + ((d << 3) + r) * 16;
            float acc = 0.0f;
            #pragma unroll
            for (int c = 0; c < 16; ++c) acc += tp[c] * bufA[(c << 6) + d];
            out[((size_t)(b * 512 + o)) * L_OUT + l] = acc + bias[o];
        }
        __syncthreads();
    }
}

extern "C" void kernel_launch(void* const* d_in, const int* in_sizes, int n_in,
                              void* d_out, int out_size, void* d_ws, size_t ws_size,
                              hipStream_t stream) {
    const float* x    = (const float*)d_in[0];
    const float* tw   = (const float*)d_in[1];
    const float* bias = (const float*)d_in[2];
    float* out = (float*)d_out;

    const size_t W21_B = 65536 * 2;                       // 128 KB
    const size_t W43_B = 32768 * 2;                       // 64 KB
    const size_t XT_B  = (size_t)16 * L_IN * C_IN * 2;    // 32 MB

    if (ws_size < W21_B + W43_B + XT_B) {
        dim3 grid(128, 16);
        debut_fused_kernel<<<grid, dim3(256), 0, stream>>>(x, tw, bias, out);
        return;
    }

    unsigned short* W21f = (unsigned short*)d_ws;
    unsigned short* W43f = (unsigned short*)((char*)d_ws + W21_B);
    unsigned short* xTd  = (unsigned short*)((char*)d_ws + W21_B + W43_B);

    build_wf<<<dim3(384), dim3(256), 0, stream>>>(tw, W21f, W43f);
    transpose_x<<<dim3(32, 8, 16), dim3(256), 0, stream>>>(x, xTd);
    debut_mfma<<<dim3(2048), dim3(512), 0, stream>>>(W21f, W43f, xTd, bias, out);
}

// Round 7
// 46.265 us; speedup vs baseline: 1.4441x; 1.4121x over previous
//
#include <hip/hip_runtime.h>

#define L_IN   2048
#define C_IN   512
#define L_OUT  2045
#define XT_PAD 21
#define CS     520    // xtile row stride (elems, 16B-aligned rows, uniform read spans)
#define DS2    1218   // out2 m2-stride (dwords)
#define AS2    38     // out2 a-stride (dwords)

typedef short short8 __attribute__((ext_vector_type(8)));
typedef float float4v __attribute__((ext_vector_type(4)));

__device__ __forceinline__ unsigned short bf16r(float f) {
    unsigned u = __float_as_uint(f);
    unsigned r = (u + 0x7FFFu + ((u >> 16) & 1u)) >> 16;
    return (unsigned short)r;
}

// ---------------- kernel 1: build W21/W43 in MFMA fragment layout (verified R3/R5/R6) ----
__global__ __launch_bounds__(256)
void build_wf(const float* __restrict__ tw, unsigned short* __restrict__ W21f,
              unsigned short* __restrict__ W43f) {
    int id = blockIdx.x * 256 + threadIdx.x;
    if (id < 65536) {
        int p = id & 7, lane = (id >> 3) & 63, oh = (id >> 9) & 1, g = id >> 10;
        int a = oh * 16 + (lane & 15);
        int e = ((lane >> 4) & 3) * 8 + p;
        int r2 = a >> 2, d2 = a & 3, c2 = e >> 2, c1 = e & 3;
        float v = tw[8192 + ((g * 4 + d2) * 8 + r2) * 8 + c2]
                * tw[(g * 8 + c2) * 16 + d2 * 4 + c1];
        W21f[id] = bf16r(v);
    } else if (id < 98304) {
        int id2 = id - 65536;
        int p = id2 & 7, lane = (id2 >> 3) & 63, kh = (id2 >> 9) & 1, s = id2 >> 10;
        int u = lane & 15;
        int w = kh * 32 + ((lane >> 4) & 3) * 8 + p;
        int r4 = u >> 1, hi = u & 1, d4 = hi * 32 + s, p2 = w >> 3, c3 = w & 7;
        float v = 0.f;
        #pragma unroll
        for (int lo = 0; lo < 2; ++lo)
            v += tw[32768 + (d4 * 8 + r4) * 16 + (2 * p2 + lo)]
               * tw[24576 + ((p2 * 32 + s) * 4 + (2 * lo + hi)) * 8 + c3];
        W43f[id2] = bf16r(v);
    }
}

// ---------------- kernel 2: fully fused: x -> (im2col+T2T1) -> LDS -> (T4T3) -> out ------
// xtile[l][c] bf16, l = 0..19 local rows (l0+l), CS stride.
// out2 dwords: dw(m2, a, gp) = m2*DS2 + a*AS2 + gp holds bf16 pair (m=2*m2, m=2*m2+1).
// Phase p: g = p*32 + gp, gp = wv*4 + gi. Stage-B accumulates accB over both phases.
__global__ __launch_bounds__(512)
void debut_fused_mfma(const unsigned short* __restrict__ W21f,
                      const unsigned short* __restrict__ W43f,
                      const float* __restrict__ x,
                      const float* __restrict__ bias, float* __restrict__ out) {
    __shared__ unsigned short xtile[20 * CS];   // 20800 B
    __shared__ unsigned int   out2[9736];       // 38944 B   (total 59744 B -> 2 blocks/CU)

    // XCD-aware bijective swizzle (2048 blocks, 8 XCDs, 256 each)
    const int bid = blockIdx.x;
    const int swz = (bid & 7) * 256 + (bid >> 3);
    const int lt = swz & 127, b = swz >> 7;
    const int l0 = lt * 16;
    const int t = threadIdx.x;
    const int lane = t & 63, wv = t >> 6;        // 8 waves
    const int lr = lane & 15, lh = lane >> 4;

    const float* xb = x + (size_t)b * C_IN * L_IN;

    // ---- stage x: x[b, :, l0..l0+19] -> xtile (coalesced 64B-per-row reads) ----
    {
        const int lq = t & 3;
        #pragma unroll
        for (int pass = 0; pass < 4; ++pass) {
            int cc = pass * 128 + (t >> 2);
            float4 v = *reinterpret_cast<const float4*>(xb + (size_t)cc * L_IN + l0 + lq * 4);
            int base = (lq * 4) * CS + cc;
            xtile[base         ] = bf16r(v.x);
            xtile[base + CS    ] = bf16r(v.y);
            xtile[base + 2 * CS] = bf16r(v.z);
            xtile[base + 3 * CS] = bf16r(v.w);
        }
        // tail rows 16..19 (clamped at the end of the signal; OOB rows feed masked outputs)
        int cc = t;
        int lx = l0 + 16; if (lx > L_IN - 4) lx = L_IN - 4;
        float4 v = *reinterpret_cast<const float4*>(xb + (size_t)cc * L_IN + lx);
        int base = 16 * CS + cc;
        xtile[base         ] = bf16r(v.x);
        xtile[base + CS    ] = bf16r(v.y);
        xtile[base + 2 * CS] = bf16r(v.z);
        xtile[base + 3 * CS] = bf16r(v.w);
    }

    // hoist stage-B A-operand loads (L2-resident, independent of LDS)
    short8 wa[4][2];
    #pragma unroll
    for (int si = 0; si < 4; ++si) {
        int s = wv * 4 + si;
        wa[si][0] = *(const short8*)(W43f + ((size_t)(s * 2 + 0) * 64 + lane) * 8);
        wa[si][1] = *(const short8*)(W43f + ((size_t)(s * 2 + 1) * 64 + lane) * 8);
    }

    __syncthreads();

    float4v accB[4] = {};

    #pragma unroll
    for (int p = 0; p < 2; ++p) {
        // ---- stage A: wave wv handles gp = wv*4 .. +3 (g = p*32 + gp) ----
        const int koff = 2 * p + (wv >> 2);
        const unsigned short* xrow = &xtile[(lr + koff) * CS + lh * 8];

        #pragma unroll
        for (int gi = 0; gi < 4; ++gi) {
            const int gp = wv * 4 + gi;
            const int g  = p * 32 + gp;
            short8 vfrag = *(const short8*)(xrow + (gp & 15) * 32);
            #pragma unroll
            for (int oh = 0; oh < 2; ++oh) {
                short8 wfrag = *(const short8*)(W21f + ((size_t)(g * 2 + oh) * 64 + lane) * 8);
                float4v acc = {};
                acc = __builtin_amdgcn_mfma_f32_16x16x32_bf16(vfrag, wfrag, acc, 0, 0, 0);
                // lane: a = oh*16+lr (D col), m = lh*4+i (D row) -> 2 packed b32 writes
                const int a = oh * 16 + lr;
                unsigned d0 = (unsigned)bf16r(acc[0]) | ((unsigned)bf16r(acc[1]) << 16);
                unsigned d1 = (unsigned)bf16r(acc[2]) | ((unsigned)bf16r(acc[3]) << 16);
                out2[(lh * 2 + 0) * DS2 + a * AS2 + gp] = d0;
                out2[(lh * 2 + 1) * DS2 + a * AS2 + gp] = d1;
            }
        }
        __syncthreads();

        // ---- stage B: wave wv accumulates s = wv*4 .. +3 over this phase's 32 g ----
        #pragma unroll
        for (int si = 0; si < 4; ++si) {
            const int s = wv * 4 + si;
            const int rb = (lr >> 1) * DS2 + s * AS2 + lh * 8;
            uint2 q0 = *(const uint2*)&out2[rb + 0];
            uint2 q1 = *(const uint2*)&out2[rb + 2];
            uint2 q2 = *(const uint2*)&out2[rb + 4];
            uint2 q3 = *(const uint2*)&out2[rb + 6];
            unsigned w0, w1, w2, w3;
            if (lr & 1) {
                w0 = (q0.x >> 16) | (q0.y & 0xffff0000u);
                w1 = (q1.x >> 16) | (q1.y & 0xffff0000u);
                w2 = (q2.x >> 16) | (q2.y & 0xffff0000u);
                w3 = (q3.x >> 16) | (q3.y & 0xffff0000u);
            } else {
                w0 = (q0.x & 0xffffu) | (q0.y << 16);
                w1 = (q1.x & 0xffffu) | (q1.y << 16);
                w2 = (q2.x & 0xffffu) | (q2.y << 16);
                w3 = (q3.x & 0xffffu) | (q3.y << 16);
            }
            uint4 uw{w0, w1, w2, w3};
            short8 bb = *reinterpret_cast<short8*>(&uw);
            accB[si] = __builtin_amdgcn_mfma_f32_16x16x32_bf16(wa[si][p], bb, accB[si], 0, 0, 0);
        }
        if (p == 0) __syncthreads();   // protect out2 before phase-1 overwrite
    }

    // ---- store ----
    const int lpos = l0 + lr;
    if (lpos < L_OUT) {
        #pragma unroll
        for (int si = 0; si < 4; ++si) {
            const int s = wv * 4 + si;
            #pragma unroll
            for (int i = 0; i < 4; ++i) {
                int o4 = s + 32 * (lh * 4 + i);
                out[((size_t)(b * 512 + o4)) * L_OUT + lpos] = accB[si][i] + bias[o4];
            }
        }
    }
}

// ---------------- fallback (round-1 kernel, used if ws too small) ----------------
__global__ __launch_bounds__(256)
void debut_fused_kernel(const float* __restrict__ x,
                        const float* __restrict__ tw,
                        const float* __restrict__ bias,
                        float* __restrict__ out)
{
    __shared__ float xt[C_IN * XT_PAD];
    __shared__ float bufA[2048];
    __shared__ float bufB[2048];
    const int tile = blockIdx.x, b = blockIdx.y;
    const int l0 = tile * 16;
    const int tid = threadIdx.x;
    const float* xb = x + (size_t)b * C_IN * L_IN;
    for (int idx = tid; idx < C_IN * 19; idx += 256) {
        int c = idx / 19, ll = idx - c * 19, l = l0 + ll;
        xt[c * XT_PAD + ll] = (l < L_IN) ? xb[c * L_IN + l] : 0.0f;
    }
    __syncthreads();
    const float* t1 = tw; const float* t2 = tw + 8192;
    const float* t3 = tw + 24576; const float* t4 = tw + 32768;
    for (int rr = 0; rr < 16; ++rr) {
        const int l = l0 + rr;
        if (l >= L_OUT) break;
        #pragma unroll
        for (int i = 0; i < 8; ++i) {
            int o = tid + 256 * i, gb = o >> 2, k = gb >> 7, cb = (gb & 127) << 2;
            const float4 tq = *reinterpret_cast<const float4*>(t1 + o * 4);
            const float* xp = &xt[cb * XT_PAD + rr + k];
            bufA[o] = tq.x * xp[0] + tq.y * xp[XT_PAD] + tq.z * xp[2 * XT_PAD] + tq.w * xp[3 * XT_PAD];
        }
        __syncthreads();
        #pragma unroll
        for (int i = 0; i < 8; ++i) {
            int o = tid + 256 * i, gb = o >> 5, r = (o >> 2) & 7, d = o & 3;
            const float* tp = t2 + (((gb << 2) + d) * 8 + r) * 8;
            const float* ip = &bufA[(gb << 5) + d];
            float acc = 0.0f;
            #pragma unroll
            for (int c = 0; c < 8; ++c) acc += tp[c] * ip[c << 2];
            bufB[o] = acc;
        }
        __syncthreads();
        #pragma unroll
        for (int i = 0; i < 4; ++i) {
            int o = tid + 256 * i, gb = o >> 7, r = (o >> 5) & 3, d = o & 31;
            const float* tp = t3 + (((gb << 5) + d) * 4 + r) * 8;
            const float* ip = &bufB[(gb << 8) + d];
            float acc = 0.0f;
            #pragma unroll
            for (int c = 0; c < 8; ++c) acc += tp[c] * ip[c << 5];
            bufA[o] = acc;
        }
        __syncthreads();
        #pragma unroll
        for (int i = 0; i < 2; ++i) {
            int o = tid + 256 * i, r = o >> 6, d = o & 63;
            const float* tp = t4 + ((d << 3) + r) * 16;
            float acc = 0.0f;
            #pragma unroll
            for (int c = 0; c < 16; ++c) acc += tp[c] * bufA[(c << 6) + d];
            out[((size_t)(b * 512 + o)) * L_OUT + l] = acc + bias[o];
        }
        __syncthreads();
    }
}

extern "C" void kernel_launch(void* const* d_in, const int* in_sizes, int n_in,
                              void* d_out, int out_size, void* d_ws, size_t ws_size,
                              hipStream_t stream) {
    const float* x    = (const float*)d_in[0];
    const float* tw   = (const float*)d_in[1];
    const float* bias = (const float*)d_in[2];
    float* out = (float*)d_out;

    const size_t W21_B = 65536 * 2;      // 128 KB
    const size_t W43_B = 32768 * 2;      // 64 KB

    if (ws_size < W21_B + W43_B) {
        dim3 grid(128, 16);
        debut_fused_kernel<<<grid, dim3(256), 0, stream>>>(x, tw, bias, out);
        return;
    }

    unsigned short* W21f = (unsigned short*)d_ws;
    unsigned short* W43f = (unsigned short*)((char*)d_ws + W21_B);

    build_wf<<<dim3(384), dim3(256), 0, stream>>>(tw, W21f, W43f);
    debut_fused_mfma<<<dim3(2048), dim3(512), 0, stream>>>(W21f, W43f, x, bias, out);
}